// Round 6
// baseline (509.410 us; speedup 1.0000x reference)
//
#include <hip/hip_runtime.h>

#define NEGV -10000.0f
#define BB 1024
#define TT 512
#define KK 64

typedef float vf2 __attribute__((ext_vector_type(2)));

// ---------------------------------------------------------------------------
// K0: trans = log_softmax(A + inv_mask*NEG, axis=-1).
// ---------------------------------------------------------------------------
__global__ __launch_bounds__(64)
void trans_kernel(const float* __restrict__ A, const int* __restrict__ inv,
                  float* __restrict__ trans)
{
    const int i = blockIdx.x, j = threadIdx.x;
    float x = A[i * KK + j] + (inv[i * KK + j] ? NEGV : 0.0f);
    float m = x;
    #pragma unroll
    for (int o = 32; o > 0; o >>= 1) m = fmaxf(m, __shfl_xor(m, o));
    float e = expf(x - m);
    float s = e;
    #pragma unroll
    for (int o = 32; o > 0; o >>= 1) s += __shfl_xor(s, o);
    trans[i * KK + j] = (x - m) - logf(s);
}

// ---------------------------------------------------------------------------
// K1: fused Viterbi. One wave per sequence; lane = tag j. bp bytes in LDS,
// backward = pure LDS pointer chase (R5-validated, absmax=0).
// R6: software-pipeline the alpha LDS round-trip. Per step:
//   adds+tree (consume a4 loaded LAST step) -> alpha -> ds_write bcast ->
//   ISSUE next step's 16 ds_read_b128 into a4 -> run the 126-instr argmax
//   scan in the loads' shadow (~250 cyc VALU >> 120 cyc LDS latency).
// R5 post-mortem: 847 cyc/step = 400 VALU + ~450 naked LDS latency/issue,
// because the reads were issued after the scan. DS ops from one wave
// complete in order, so write->read needs no explicit wait; wave_barrier
// fences pin program order against compiler sinking.
// ---------------------------------------------------------------------------
__global__ __launch_bounds__(64, 1)
void viterbi_kernel(const float* __restrict__ unary, const int* __restrict__ lengths,
                    const float* __restrict__ trans, int* __restrict__ out)
{
    const int lane = threadIdx.x;
    const int b = blockIdx.x;

    __shared__ unsigned char sbp[(TT - 1) * KK];   // bp rows t=2..512 -> [(t-2)*64+j]
    __shared__ float sAf[2 * KK];                  // alpha broadcast, double-buffered

    // Treg2[i] = {trans[2i][lane], trans[2i+1][lane]}  (coalesced loads)
    vf2 Treg2[KK / 2];
    #pragma unroll
    for (int i = 0; i < KK / 2; ++i) {
        Treg2[i].x = trans[(2 * i)     * KK + lane];
        Treg2[i].y = trans[(2 * i + 1) * KK + lane];
    }

    const int len = lengths[b];                    // 1..512, wave-uniform
    const float* ur = unary + (long)b * (TT * KK);
    int* orow = out + b * TT;

    float uring[8];                                // slot k: unary row t-1, t = tb+k
    #pragma unroll
    for (int d = 0; d < 8; ++d) uring[d] = ur[d * KK + lane];

    float alpha = (lane == 1) ? 0.0f : NEGV;       // GO frame
    sAf[lane] = alpha;                             // buffer 0 holds alpha_0
    __builtin_amdgcn_wave_barrier();

    // prologue: preload a4 with alpha_0 broadcast (consumed at t=1)
    float4 a4[16];
    {
        const float4* p0 = (const float4*)(sAf);
        #pragma unroll
        for (int i = 0; i < 16; ++i) a4[i] = p0[i];
    }
    __builtin_amdgcn_wave_barrier();

    for (int tb = 1; tb <= len; tb += 8) {         // tb odd -> parities compile-time
        #pragma unroll
        for (int k = 0; k < 8; ++k) {
            const int t = tb + k;                  // wave-uniform
            const int q = (k + 1) & 1;             // output buffer parity (t odd -> 1)

            // scores sv[i] = alpha_{t-1}[i] + trans[i][lane]   (a4 = last step's loads)
            float sv[KK];
            #pragma unroll
            for (int i4 = 0; i4 < 16; ++i4) {
                vf2 t01 = vf2{a4[i4].x, a4[i4].y} + Treg2[2 * i4];
                vf2 t23 = vf2{a4[i4].z, a4[i4].w} + Treg2[2 * i4 + 1];
                sv[4 * i4 + 0] = t01.x; sv[4 * i4 + 1] = t01.y;
                sv[4 * i4 + 2] = t23.x; sv[4 * i4 + 3] = t23.y;
            }

            // m = max_i sv[i] — max3 tree, depth 4
            float l0[22];
            #pragma unroll
            for (int i = 0; i < 21; ++i)
                l0[i] = fmaxf(fmaxf(sv[3 * i], sv[3 * i + 1]), sv[3 * i + 2]);
            l0[21] = sv[63];
            float l1[8];
            #pragma unroll
            for (int i = 0; i < 7; ++i)
                l1[i] = fmaxf(fmaxf(l0[3 * i], l0[3 * i + 1]), l0[3 * i + 2]);
            l1[7] = l0[21];
            float l2a = fmaxf(fmaxf(l1[0], l1[1]), l1[2]);
            float l2b = fmaxf(fmaxf(l1[3], l1[4]), l1[5]);
            float m   = fmaxf(fmaxf(l2a, l2b), fmaxf(l1[6], l1[7]));

            // alpha_t, broadcast write, and IMMEDIATELY issue next step's reads
            if (t <= len) alpha = m + uring[k];
            sAf[q * KK + lane] = alpha;
            __builtin_amdgcn_wave_barrier();       // write before reads (DS in-order)
            {
                const float4* p = (const float4*)(sAf + q * KK);
                #pragma unroll
                for (int i = 0; i < 16; ++i) a4[i] = p[i];
            }
            __builtin_amdgcn_wave_barrier();       // loads stay above the scan

            // ring refill (row t+7, clamped; off critical path)
            { int rn = t + 7; if (rn > TT - 1) rn = TT - 1;
              uring[k] = ur[rn * KK + lane]; }

            // first-index argmax scan runs in the shadow of the in-flight reads
            // (m is bitwise one of sv; descending cndmask chain -> smallest i,
            //  exact jnp.argmax tie semantics — validated absmax=0 in R5)
            int idx = 63;
            #pragma unroll
            for (int i = 62; i >= 0; --i) idx = (sv[i] == m) ? i : idx;
            if (t >= 2 && t <= len)
                sbp[(t - 2) * KK + lane] = (unsigned char)idx;
        }
    }

    // last = first-index argmax of final alpha
    float mm = alpha;
    #pragma unroll
    for (int o = 32; o > 0; o >>= 1) mm = fmaxf(mm, __shfl_xor(mm, o));
    unsigned long long msk = __ballot(alpha == mm);
    int last = __ffsll(msk) - 1;

    // positions >= len-1 carry `last`
    for (int jj = len - 1 + lane; jj < TT; jj += 64) orow[jj] = last;

    // backward: pure LDS chase
    int tag = last;
    for (int t = len; t >= 2; --t) {
        int prev = sbp[(t - 2) * KK + tag];        // same-address broadcast read
        if (lane == 0) orow[t - 2] = prev;
        tag = prev;
    }
}

extern "C" void kernel_launch(void* const* d_in, const int* in_sizes, int n_in,
                              void* d_out, int out_size, void* d_ws, size_t ws_size,
                              hipStream_t stream)
{
    const float* unary   = (const float*)d_in[0];
    const int*   lengths = (const int*)d_in[1];
    const int*   inv     = (const int*)d_in[2];
    const float* A       = (const float*)d_in[3];
    int*         out     = (int*)d_out;

    float* trans = (float*)d_ws;                   // 4096 floats = 16 KB

    trans_kernel<<<KK, KK, 0, stream>>>(A, inv, trans);
    viterbi_kernel<<<BB, KK, 0, stream>>>(unary, lengths, trans, out);
}